// Round 6
// baseline (158.997 us; speedup 1.0000x reference)
//
#include <hip/hip_runtime.h>

// W4A16 GEMM, M=N=K=4096, GROUP=128, zp=8.
// Inputs (harness presents fp16 as f32): x f32[M,K], scale f32[32,N],
// q_weight int32[K,N] (0..15). Output f32[M,N].
//
// Fast path (ws >= 64MB):
//   P0 convert_x: x f32 -> Xh fp16 [M,K]
//   P1 dequant_transpose: q -> Wt fp16 [N,K]
//   P2 gemm_8p: 256x256 tile, BK=64, 8 waves, double-buffered LDS,
//      4-phase-per-K-tile interleave (T3), counted vmcnt(8) (T4), read-side
//      XOR swizzle (T2, conflicts=0 verified r5), setprio on MFMA (T5),
//      XCD-aware block swizzle (T1).
// Fallback (ws >= 32MB): proven round-3 reg-staged 128x128 GEMM.

#define MDIM 4096
#define NDIM 4096
#define KDIM 4096

typedef __attribute__((ext_vector_type(8))) _Float16 f16x8;
typedef __attribute__((ext_vector_type(4))) float    f32x4;
typedef __attribute__((ext_vector_type(4))) int      i32x4;

__device__ __forceinline__ unsigned short f2h(float f) {
    union { _Float16 h; unsigned short u; } v;
    v.h = (_Float16)f;  // RNE
    return v.u;
}

// ---------------- diagnostic fallback ----------------
__global__ void zero_fill(float* __restrict__ out, int n) {
    int i = blockIdx.x * blockDim.x + threadIdx.x;
    if (i < n) out[i] = 0.f;
}

// ---------------- P0: x f32 -> fp16 ----------------
__global__ void convert_x(const float* __restrict__ x,
                          unsigned short* __restrict__ xh, int n8) {
    int i = blockIdx.x * blockDim.x + threadIdx.x;
    const int stride = gridDim.x * blockDim.x;
    for (; i < n8; i += stride) {
        const float4 a = ((const float4*)x)[(size_t)i * 2];
        const float4 b = ((const float4*)x)[(size_t)i * 2 + 1];
        f16x8 r;
        r[0] = (_Float16)a.x; r[1] = (_Float16)a.y;
        r[2] = (_Float16)a.z; r[3] = (_Float16)a.w;
        r[4] = (_Float16)b.x; r[5] = (_Float16)b.y;
        r[6] = (_Float16)b.z; r[7] = (_Float16)b.w;
        *(f16x8*)&xh[(size_t)i * 8] = r;
    }
}

// ---------------- P1: dequant + transpose ----------------
__global__ void dequant_transpose(const int* __restrict__ q,
                                  const float* __restrict__ scale,
                                  unsigned short* __restrict__ wt) {
    __shared__ unsigned short lds[64][65];
    const int t  = threadIdx.x;
    const int k0 = blockIdx.x * 64;
    const int n0 = blockIdx.y * 64;
    const int g  = k0 >> 7;

    const int r  = t >> 4;
    const int c4 = (t & 15) * 4;

    float4 s = *(const float4*)&scale[(size_t)g * NDIM + n0 + c4];

#pragma unroll
    for (int p = 0; p < 4; ++p) {
        const int kl = r + p * 16;
        int4 qv = *(const int4*)&q[(size_t)(k0 + kl) * NDIM + n0 + c4];
        lds[kl][c4 + 0] = f2h((float)(qv.x - 8) * s.x);
        lds[kl][c4 + 1] = f2h((float)(qv.y - 8) * s.y);
        lds[kl][c4 + 2] = f2h((float)(qv.z - 8) * s.z);
        lds[kl][c4 + 3] = f2h((float)(qv.w - 8) * s.w);
    }
    __syncthreads();

    const int kc = (t & 15) * 4;
#pragma unroll
    for (int p = 0; p < 4; ++p) {
        const int nl = (t >> 4) + p * 16;
        ushort4 o;
        o.x = lds[kc + 0][nl];
        o.y = lds[kc + 1][nl];
        o.z = lds[kc + 2][nl];
        o.w = lds[kc + 3][nl];
        *(ushort4*)&wt[(size_t)(n0 + nl) * KDIM + k0 + kc] = o;
    }
}

// ---------------- P2 fast: 256x256 8-wave 4-phase GEMM ----------------
// Per K-tile phases (MFMA quadrants of the wave's 128x64 output):
//   P0: ds_read a[0-3] (8) + b[0-1] (4) -> Q(mi0-3, ni0-1)
//   P1: ds_read a[4-7] (8)              -> Q(mi4-7, ni0-1)
//   P2: stageA(kt+2) + ds_read b[2-3]   -> Q(mi0-3, ni2-3)
//   P3: stageB(kt+2)                    -> Q(mi4-7, ni2-3)
// Safety: stageA at P2 top is after P1-end barrier (all waves' sA reads done:
// a4-7 consumed before P1's MFMA via lgkmcnt(0)). stageB at P3 top is after
// P2-end barrier (b2-3 were the last sB reads). vmcnt: 16 outstanding at tile
// top (tiles kt, kt+1), vmcnt(8) => tile kt fully landed; barrier makes it
// block-wide. Last tile: vmcnt(0).
__global__ __launch_bounds__(512, 2) void gemm_8p(const unsigned short* __restrict__ A,
                                                  const unsigned short* __restrict__ Bt,
                                                  float* __restrict__ C) {
    __shared__ unsigned short lds[65536];  // 128 KiB: 2 x (A 16384 + B 16384)

    const int t = threadIdx.x;
    const int w = t >> 6;   // wave 0..7
    const int l = t & 63;

    // XCD-aware bijective swizzle: 256 wgs, 8 XCDs -> 32 contiguous tiles/XCD
    const int orig = blockIdx.x;
    const int wg = (orig & 7) * 32 + (orig >> 3);
    const int bx = wg & 15;   // N tile
    const int by = wg >> 4;   // M tile
    const int m0 = by * 256;
    const int n0 = bx * 256;

    const int wr = w >> 2;    // 0..1 : wave row (128 rows)
    const int wc = w & 3;     // 0..3 : wave col (64 cols)

    // ---- staging geometry (per-lane, swizzled source; LDS dest linear) ----
    const int lr8 = l >> 3;                  // row within 8-row group
    const int sc  = ((l & 7) ^ lr8) * 8;     // swizzled source col (halfs)
    const unsigned short* pa = A  + (size_t)(m0 + w * 8 + lr8) * KDIM + sc;
    const unsigned short* pb = Bt + (size_t)(n0 + w * 8 + lr8) * KDIM + sc;

    auto stageA = [&](int buf, int kt) {
        const int kof = kt * 64;
        unsigned short* base = &lds[buf * 32768];
#pragma unroll
        for (int i = 0; i < 4; ++i)
            __builtin_amdgcn_global_load_lds(
                (const __attribute__((address_space(1))) unsigned int*)(pa + (size_t)i * 64 * KDIM + kof),
                (__attribute__((address_space(3))) unsigned int*)(base + i * 4096 + w * 512), 16, 0, 0);
    };
    auto stageB = [&](int buf, int kt) {
        const int kof = kt * 64;
        unsigned short* base = &lds[buf * 32768 + 16384];
#pragma unroll
        for (int i = 0; i < 4; ++i)
            __builtin_amdgcn_global_load_lds(
                (const __attribute__((address_space(1))) unsigned int*)(pb + (size_t)i * 64 * KDIM + kof),
                (__attribute__((address_space(3))) unsigned int*)(base + i * 4096 + w * 512), 16, 0, 0);
    };

    // ---- fragment-read geometry ----
    const int lr = l & 15;    // frag row
    const int hi = l >> 4;    // 0..3 : k sub-chunk
    const int ca0 = ((hi + 0) ^ (l & 7)) * 8;  // phys chunk offset, k-step 0
    const int ca1 = ((hi + 4) ^ (l & 7)) * 8;  // phys chunk offset, k-step 1
    const int arow = wr * 128 + lr;
    const int brow = wc * 64 + lr;

    f32x4 acc[8][4];
#pragma unroll
    for (int mi = 0; mi < 8; ++mi)
#pragma unroll
        for (int ni = 0; ni < 4; ++ni)
            acc[mi][ni] = (f32x4){0.f, 0.f, 0.f, 0.f};

    f16x8 a[8][2], b[4][2];

#define READ_A(MI0)                                                         \
    _Pragma("unroll")                                                       \
    for (int mi = MI0; mi < MI0 + 4; ++mi) {                                \
        a[mi][0] = *(const f16x8*)&sA[(arow + mi * 16) * 64 + ca0];         \
        a[mi][1] = *(const f16x8*)&sA[(arow + mi * 16) * 64 + ca1];         \
    }
#define READ_B(NI0)                                                         \
    _Pragma("unroll")                                                       \
    for (int ni = NI0; ni < NI0 + 2; ++ni) {                                \
        b[ni][0] = *(const f16x8*)&sB[(brow + ni * 16) * 64 + ca0];         \
        b[ni][1] = *(const f16x8*)&sB[(brow + ni * 16) * 64 + ca1];         \
    }
#define QUAD(MI0, NI0)                                                      \
    __builtin_amdgcn_s_setprio(1);                                          \
    _Pragma("unroll")                                                       \
    for (int kk = 0; kk < 2; ++kk)                                          \
        _Pragma("unroll")                                                   \
        for (int mi = MI0; mi < MI0 + 4; ++mi)                              \
            _Pragma("unroll")                                               \
            for (int ni = NI0; ni < NI0 + 2; ++ni)                          \
                acc[mi][ni] = __builtin_amdgcn_mfma_f32_16x16x32_f16(       \
                    a[mi][kk], b[ni][kk], acc[mi][ni], 0, 0, 0);            \
    __builtin_amdgcn_s_setprio(0);

    stageA(0, 0); stageB(0, 0);
    stageA(1, 1); stageB(1, 1);

    const int NT = KDIM / 64;  // 64
    for (int kt = 0; kt < NT; ++kt) {
        if (kt == NT - 1)
            asm volatile("s_waitcnt vmcnt(0)" ::: "memory");
        else
            asm volatile("s_waitcnt vmcnt(8)" ::: "memory");  // tile kt landed
        __builtin_amdgcn_s_barrier();

        const int bsel = kt & 1;
        const unsigned short* sA = &lds[bsel * 32768];
        const unsigned short* sB = &lds[bsel * 32768 + 16384];
        const bool pre = (kt + 2 < NT);

        // ---- phase 0 ----
        READ_A(0); READ_B(0);
        __builtin_amdgcn_s_barrier();
        asm volatile("s_waitcnt lgkmcnt(0)" ::: "memory");
        QUAD(0, 0);
        __builtin_amdgcn_s_barrier();

        // ---- phase 1 ----
        READ_A(4);
        __builtin_amdgcn_s_barrier();
        asm volatile("s_waitcnt lgkmcnt(0)" ::: "memory");
        QUAD(4, 0);
        __builtin_amdgcn_s_barrier();

        // ---- phase 2 ---- (all sA reads of this tile done at P1-end barrier)
        if (pre) stageA(bsel, kt + 2);
        READ_B(2);
        __builtin_amdgcn_s_barrier();
        asm volatile("s_waitcnt lgkmcnt(0)" ::: "memory");
        QUAD(0, 2);
        __builtin_amdgcn_s_barrier();

        // ---- phase 3 ---- (all sB reads of this tile done at P2-end barrier)
        if (pre) stageB(bsel, kt + 2);
        QUAD(4, 2);
        // next-iteration top vmcnt+barrier closes this phase
    }

#undef READ_A
#undef READ_B
#undef QUAD

    // epilogue: D layout col = lane&15, row = (lane>>4)*4 + reg
#pragma unroll
    for (int mi = 0; mi < 8; ++mi) {
#pragma unroll
        for (int ni = 0; ni < 4; ++ni) {
            const int row = m0 + wr * 128 + mi * 16 + hi * 4;
            const int col = n0 + wc * 64 + ni * 16 + lr;
#pragma unroll
            for (int r2 = 0; r2 < 4; ++r2)
                C[(size_t)(row + r2) * NDIM + col] = acc[mi][ni][r2];
        }
    }
}

// ---------------- P2 fallback: round-3 reg-staged GEMM (proven) ----------------
__global__ __launch_bounds__(256) void gemm_bt(const float* __restrict__ A,
                                               const unsigned short* __restrict__ Bt,
                                               float* __restrict__ C) {
    __shared__ unsigned short sA[2][128 * 32];
    __shared__ unsigned short sB[2][128 * 32];

    const int t = threadIdx.x;
    const int l = t & 63;
    const int w = t >> 6;

    const int m0 = blockIdx.y * 128;
    const int n0 = blockIdx.x * 128;

    const float*          Arow = A  + (size_t)m0 * KDIM;
    const unsigned short* Brow = Bt + (size_t)n0 * KDIM;

    const int r0 = t >> 2;
    const int c0 = (t & 3) * 8;

    float4 fa[4];
    i32x4  pb0, pb1;
    auto gload = [&](int kt) {
        const size_t oa0 = (size_t)r0 * KDIM + (size_t)kt * 32 + c0;
        const size_t oa1 = (size_t)(r0 + 64) * KDIM + (size_t)kt * 32 + c0;
        fa[0] = *(const float4*)(Arow + oa0);
        fa[1] = *(const float4*)(Arow + oa0 + 4);
        fa[2] = *(const float4*)(Arow + oa1);
        fa[3] = *(const float4*)(Arow + oa1 + 4);
        pb0 = *(const i32x4*)(Brow + oa0);
        pb1 = *(const i32x4*)(Brow + oa1);
    };
    auto pack8 = [&](float4 a, float4 b) {
        f16x8 r;
        r[0] = (_Float16)a.x; r[1] = (_Float16)a.y;
        r[2] = (_Float16)a.z; r[3] = (_Float16)a.w;
        r[4] = (_Float16)b.x; r[5] = (_Float16)b.y;
        r[6] = (_Float16)b.z; r[7] = (_Float16)b.w;
        return r;
    };
    auto swrite = [&](int buf) {
        *(f16x8*)&sA[buf][r0 * 32 + c0]        = pack8(fa[0], fa[1]);
        *(f16x8*)&sA[buf][(r0 + 64) * 32 + c0] = pack8(fa[2], fa[3]);
        *(i32x4*)&sB[buf][r0 * 32 + c0]        = pb0;
        *(i32x4*)&sB[buf][(r0 + 64) * 32 + c0] = pb1;
    };

    f32x4 acc[4][4];
#pragma unroll
    for (int mi = 0; mi < 4; ++mi)
#pragma unroll
        for (int ni = 0; ni < 4; ++ni)
            acc[mi][ni] = (f32x4){0.f, 0.f, 0.f, 0.f};

    const int wm = (w >> 1) * 64;
    const int wn = (w & 1) * 64;
    const int lr = l & 15;
    const int lk = (l >> 4) * 8;

    gload(0);
    swrite(0);

    const int NT = KDIM / 32;
    for (int kt = 0; kt < NT; ++kt) {
        const int cur = kt & 1;
        __syncthreads();
        if (kt + 1 < NT) gload(kt + 1);

        f16x8 a[4], b[4];
#pragma unroll
        for (int mi = 0; mi < 4; ++mi)
            a[mi] = *(const f16x8*)&sA[cur][(wm + mi * 16 + lr) * 32 + lk];
#pragma unroll
        for (int ni = 0; ni < 4; ++ni)
            b[ni] = *(const f16x8*)&sB[cur][(wn + ni * 16 + lr) * 32 + lk];

#pragma unroll
        for (int mi = 0; mi < 4; ++mi)
#pragma unroll
            for (int ni = 0; ni < 4; ++ni)
                acc[mi][ni] = __builtin_amdgcn_mfma_f32_16x16x32_f16(
                    a[mi], b[ni], acc[mi][ni], 0, 0, 0);

        if (kt + 1 < NT) swrite(cur ^ 1);
    }

#pragma unroll
    for (int mi = 0; mi < 4; ++mi) {
#pragma unroll
        for (int ni = 0; ni < 4; ++ni) {
            const int row = m0 + wm + mi * 16 + (l >> 4) * 4;
            const int col = n0 + wn + ni * 16 + lr;
#pragma unroll
            for (int r2 = 0; r2 < 4; ++r2)
                C[(size_t)(row + r2) * NDIM + col] = acc[mi][ni][r2];
        }
    }
}

extern "C" void kernel_launch(void* const* d_in, const int* in_sizes, int n_in,
                              void* d_out, int out_size, void* d_ws, size_t ws_size,
                              hipStream_t stream) {
    const float* x     = (const float*)d_in[0];
    const float* scale = (const float*)d_in[1];
    const int*   qw    = (const int*)d_in[2];
    float*       out   = (float*)d_out;

    const size_t wtBytes = (size_t)NDIM * KDIM * 2;  // 32 MB
    const size_t xhBytes = (size_t)MDIM * KDIM * 2;  // 32 MB

    if (ws_size >= wtBytes + xhBytes) {
        unsigned short* wt = (unsigned short*)d_ws;
        unsigned short* xh = (unsigned short*)((char*)d_ws + wtBytes);
        convert_x<<<2048, 256, 0, stream>>>(x, xh, MDIM * KDIM / 8);
        dequant_transpose<<<dim3(KDIM / 64, NDIM / 64), 256, 0, stream>>>(qw, scale, wt);
        gemm_8p<<<dim3(256), 512, 0, stream>>>(xh, wt, out);
    } else if (ws_size >= wtBytes) {
        unsigned short* wt = (unsigned short*)d_ws;
        dequant_transpose<<<dim3(KDIM / 64, NDIM / 64), 256, 0, stream>>>(qw, scale, wt);
        gemm_bt<<<dim3(NDIM / 128, MDIM / 128), 256, 0, stream>>>(x, wt, out);
    } else {
        zero_fill<<<(out_size + 255) / 256, 256, 0, stream>>>(out, out_size);
    }
}

// Round 7
// 156.832 us; speedup vs baseline: 1.0138x; 1.0138x over previous
//
#include <hip/hip_runtime.h>

// W4A16 GEMM, M=N=K=4096, GROUP=128, zp=8.
// Inputs (harness presents fp16 as f32): x f32[M,K], scale f32[32,N],
// q_weight int32[K,N] (0..15). Output f32[M,N].
//
// Fast path (ws >= 64MB):
//   P0 convert_x: x f32 -> Xh fp16 [M,K]
//   P1 dequant_transpose: q -> Wt fp16 [N,K]
//   P2 gemm_il: 256x256 tile, BK=64, 8 waves, double-buffered LDS, counted
//      vmcnt(8) (T4), read-side XOR swizzle (T2, conflicts=0 verified r5),
//      XCD swizzle (T1). NEW vs r6: no intra-tile barriers/lgkm walls —
//      ds_reads stream 2-frags-ahead of MFMA clusters in one straight-line
//      region; compiler emits counted lgkmcnt -> LDS pipe overlaps MFMA pipe.
// Fallback (ws >= 32MB): proven round-3 reg-staged 128x128 GEMM.

#define MDIM 4096
#define NDIM 4096
#define KDIM 4096

typedef __attribute__((ext_vector_type(8))) _Float16 f16x8;
typedef __attribute__((ext_vector_type(4))) float    f32x4;
typedef __attribute__((ext_vector_type(4))) int      i32x4;

__device__ __forceinline__ unsigned short f2h(float f) {
    union { _Float16 h; unsigned short u; } v;
    v.h = (_Float16)f;  // RNE
    return v.u;
}

// ---------------- diagnostic fallback ----------------
__global__ void zero_fill(float* __restrict__ out, int n) {
    int i = blockIdx.x * blockDim.x + threadIdx.x;
    if (i < n) out[i] = 0.f;
}

// ---------------- P0: x f32 -> fp16 ----------------
__global__ void convert_x(const float* __restrict__ x,
                          unsigned short* __restrict__ xh, int n8) {
    int i = blockIdx.x * blockDim.x + threadIdx.x;
    const int stride = gridDim.x * blockDim.x;
    for (; i < n8; i += stride) {
        const float4 a = ((const float4*)x)[(size_t)i * 2];
        const float4 b = ((const float4*)x)[(size_t)i * 2 + 1];
        f16x8 r;
        r[0] = (_Float16)a.x; r[1] = (_Float16)a.y;
        r[2] = (_Float16)a.z; r[3] = (_Float16)a.w;
        r[4] = (_Float16)b.x; r[5] = (_Float16)b.y;
        r[6] = (_Float16)b.z; r[7] = (_Float16)b.w;
        *(f16x8*)&xh[(size_t)i * 8] = r;
    }
}

// ---------------- P1: dequant + transpose ----------------
__global__ void dequant_transpose(const int* __restrict__ q,
                                  const float* __restrict__ scale,
                                  unsigned short* __restrict__ wt) {
    __shared__ unsigned short lds[64][65];
    const int t  = threadIdx.x;
    const int k0 = blockIdx.x * 64;
    const int n0 = blockIdx.y * 64;
    const int g  = k0 >> 7;

    const int r  = t >> 4;
    const int c4 = (t & 15) * 4;

    float4 s = *(const float4*)&scale[(size_t)g * NDIM + n0 + c4];

#pragma unroll
    for (int p = 0; p < 4; ++p) {
        const int kl = r + p * 16;
        int4 qv = *(const int4*)&q[(size_t)(k0 + kl) * NDIM + n0 + c4];
        lds[kl][c4 + 0] = f2h((float)(qv.x - 8) * s.x);
        lds[kl][c4 + 1] = f2h((float)(qv.y - 8) * s.y);
        lds[kl][c4 + 2] = f2h((float)(qv.z - 8) * s.z);
        lds[kl][c4 + 3] = f2h((float)(qv.w - 8) * s.w);
    }
    __syncthreads();

    const int kc = (t & 15) * 4;
#pragma unroll
    for (int p = 0; p < 4; ++p) {
        const int nl = (t >> 4) + p * 16;
        ushort4 o;
        o.x = lds[kc + 0][nl];
        o.y = lds[kc + 1][nl];
        o.z = lds[kc + 2][nl];
        o.w = lds[kc + 3][nl];
        *(ushort4*)&wt[(size_t)(n0 + nl) * KDIM + k0 + kc] = o;
    }
}

// ---------------- P2 fast: 256x256 8-wave interleaved GEMM ----------------
// Per K-tile: vmcnt(8)+barrier (buf staged) -> straight-line {8 B-frag reads,
// A-frags streamed 2 mi ahead, 8-MFMA cluster per mi} -> barrier (all reads
// done: every read is consumed by an MFMA before the barrier) -> stage(kt+2)
// into the buffer just freed. Loads stay >=8 deep in flight (never drained).
__global__ __launch_bounds__(512, 2) void gemm_il(const unsigned short* __restrict__ A,
                                                  const unsigned short* __restrict__ Bt,
                                                  float* __restrict__ C) {
    __shared__ unsigned short lds[65536];  // 128 KiB: 2 x (A 16384 + B 16384)

    const int t = threadIdx.x;
    const int w = t >> 6;   // wave 0..7
    const int l = t & 63;

    // XCD-aware bijective swizzle: 256 wgs, 8 XCDs -> 32 contiguous tiles/XCD
    const int orig = blockIdx.x;
    const int wg = (orig & 7) * 32 + (orig >> 3);
    const int bx = wg & 15;   // N tile
    const int by = wg >> 4;   // M tile
    const int m0 = by * 256;
    const int n0 = bx * 256;

    const int wr = w >> 2;    // 0..1 : wave row (128 rows)
    const int wc = w & 3;     // 0..3 : wave col (64 cols)

    // ---- staging geometry (per-lane swizzled source; LDS dest linear) ----
    const int lr8 = l >> 3;                  // row within 8-row group
    const int sc  = ((l & 7) ^ lr8) * 8;     // swizzled source col (halfs)
    const unsigned short* pa = A  + (size_t)(m0 + w * 8 + lr8) * KDIM + sc;
    const unsigned short* pb = Bt + (size_t)(n0 + w * 8 + lr8) * KDIM + sc;

    auto stage = [&](int buf, int kt) {
        const int kof = kt * 64;
        unsigned short* base = &lds[buf * 32768];
#pragma unroll
        for (int i = 0; i < 4; ++i)
            __builtin_amdgcn_global_load_lds(
                (const __attribute__((address_space(1))) unsigned int*)(pa + (size_t)i * 64 * KDIM + kof),
                (__attribute__((address_space(3))) unsigned int*)(base + i * 4096 + w * 512), 16, 0, 0);
#pragma unroll
        for (int i = 0; i < 4; ++i)
            __builtin_amdgcn_global_load_lds(
                (const __attribute__((address_space(1))) unsigned int*)(pb + (size_t)i * 64 * KDIM + kof),
                (__attribute__((address_space(3))) unsigned int*)(base + 16384 + i * 4096 + w * 512), 16, 0, 0);
    };

    // ---- fragment-read geometry ----
    const int lr = l & 15;    // frag row
    const int hi = l >> 4;    // 0..3 : k sub-chunk
    const int ca0 = ((hi + 0) ^ (l & 7)) * 8;  // phys chunk offset, k-step 0
    const int ca1 = ((hi + 4) ^ (l & 7)) * 8;  // phys chunk offset, k-step 1
    const int arow = wr * 128 + lr;
    const int brow = wc * 64 + lr;

    f32x4 acc[8][4];
#pragma unroll
    for (int mi = 0; mi < 8; ++mi)
#pragma unroll
        for (int ni = 0; ni < 4; ++ni)
            acc[mi][ni] = (f32x4){0.f, 0.f, 0.f, 0.f};

    stage(0, 0);
    stage(1, 1);

    const int NT = KDIM / 64;  // 64
    for (int kt = 0; kt < NT; ++kt) {
        if (kt == NT - 1)
            asm volatile("s_waitcnt vmcnt(0)" ::: "memory");
        else
            asm volatile("s_waitcnt vmcnt(8)" ::: "memory");  // tile kt landed
        __builtin_amdgcn_s_barrier();                          // block-wide: buf ready

        const int bsel = kt & 1;
        const unsigned short* sA = &lds[bsel * 32768];
        const unsigned short* sB = &lds[bsel * 32768 + 16384];

        // ---- straight-line tile body: compiler schedules reads vs MFMA ----
        f16x8 bf[4][2], af[8][2];
#pragma unroll
        for (int ni = 0; ni < 4; ++ni) {
            bf[ni][0] = *(const f16x8*)&sB[(brow + ni * 16) * 64 + ca0];
            bf[ni][1] = *(const f16x8*)&sB[(brow + ni * 16) * 64 + ca1];
        }
#pragma unroll
        for (int mi = 0; mi < 2; ++mi) {
            af[mi][0] = *(const f16x8*)&sA[(arow + mi * 16) * 64 + ca0];
            af[mi][1] = *(const f16x8*)&sA[(arow + mi * 16) * 64 + ca1];
        }
#pragma unroll
        for (int mi = 0; mi < 8; ++mi) {
            if (mi < 6) {
                af[mi + 2][0] = *(const f16x8*)&sA[(arow + (mi + 2) * 16) * 64 + ca0];
                af[mi + 2][1] = *(const f16x8*)&sA[(arow + (mi + 2) * 16) * 64 + ca1];
            }
            __builtin_amdgcn_s_setprio(1);
#pragma unroll
            for (int kk = 0; kk < 2; ++kk)
#pragma unroll
                for (int ni = 0; ni < 4; ++ni)
                    acc[mi][ni] = __builtin_amdgcn_mfma_f32_16x16x32_f16(
                        af[mi][kk], bf[ni][kk], acc[mi][ni], 0, 0, 0);
            __builtin_amdgcn_s_setprio(0);
        }

        __builtin_amdgcn_s_barrier();          // all waves done reading buf bsel
        if (kt + 2 < NT) stage(bsel, kt + 2);  // overwrite freed buf; awaited kt+2
    }

    // epilogue: D layout col = lane&15, row = (lane>>4)*4 + reg
#pragma unroll
    for (int mi = 0; mi < 8; ++mi) {
#pragma unroll
        for (int ni = 0; ni < 4; ++ni) {
            const int row = m0 + wr * 128 + mi * 16 + hi * 4;
            const int col = n0 + wc * 64 + ni * 16 + lr;
#pragma unroll
            for (int r2 = 0; r2 < 4; ++r2)
                C[(size_t)(row + r2) * NDIM + col] = acc[mi][ni][r2];
        }
    }
}

// ---------------- P2 fallback: round-3 reg-staged GEMM (proven) ----------------
__global__ __launch_bounds__(256) void gemm_bt(const float* __restrict__ A,
                                               const unsigned short* __restrict__ Bt,
                                               float* __restrict__ C) {
    __shared__ unsigned short sA[2][128 * 32];
    __shared__ unsigned short sB[2][128 * 32];

    const int t = threadIdx.x;
    const int l = t & 63;
    const int w = t >> 6;

    const int m0 = blockIdx.y * 128;
    const int n0 = blockIdx.x * 128;

    const float*          Arow = A  + (size_t)m0 * KDIM;
    const unsigned short* Brow = Bt + (size_t)n0 * KDIM;

    const int r0 = t >> 2;
    const int c0 = (t & 3) * 8;

    float4 fa[4];
    i32x4  pb0, pb1;
    auto gload = [&](int kt) {
        const size_t oa0 = (size_t)r0 * KDIM + (size_t)kt * 32 + c0;
        const size_t oa1 = (size_t)(r0 + 64) * KDIM + (size_t)kt * 32 + c0;
        fa[0] = *(const float4*)(Arow + oa0);
        fa[1] = *(const float4*)(Arow + oa0 + 4);
        fa[2] = *(const float4*)(Arow + oa1);
        fa[3] = *(const float4*)(Arow + oa1 + 4);
        pb0 = *(const i32x4*)(Brow + oa0);
        pb1 = *(const i32x4*)(Brow + oa1);
    };
    auto pack8 = [&](float4 a, float4 b) {
        f16x8 r;
        r[0] = (_Float16)a.x; r[1] = (_Float16)a.y;
        r[2] = (_Float16)a.z; r[3] = (_Float16)a.w;
        r[4] = (_Float16)b.x; r[5] = (_Float16)b.y;
        r[6] = (_Float16)b.z; r[7] = (_Float16)b.w;
        return r;
    };
    auto swrite = [&](int buf) {
        *(f16x8*)&sA[buf][r0 * 32 + c0]        = pack8(fa[0], fa[1]);
        *(f16x8*)&sA[buf][(r0 + 64) * 32 + c0] = pack8(fa[2], fa[3]);
        *(i32x4*)&sB[buf][r0 * 32 + c0]        = pb0;
        *(i32x4*)&sB[buf][(r0 + 64) * 32 + c0] = pb1;
    };

    f32x4 acc[4][4];
#pragma unroll
    for (int mi = 0; mi < 4; ++mi)
#pragma unroll
        for (int ni = 0; ni < 4; ++ni)
            acc[mi][ni] = (f32x4){0.f, 0.f, 0.f, 0.f};

    const int wm = (w >> 1) * 64;
    const int wn = (w & 1) * 64;
    const int lr = l & 15;
    const int lk = (l >> 4) * 8;

    gload(0);
    swrite(0);

    const int NT = KDIM / 32;
    for (int kt = 0; kt < NT; ++kt) {
        const int cur = kt & 1;
        __syncthreads();
        if (kt + 1 < NT) gload(kt + 1);

        f16x8 a[4], b[4];
#pragma unroll
        for (int mi = 0; mi < 4; ++mi)
            a[mi] = *(const f16x8*)&sA[cur][(wm + mi * 16 + lr) * 32 + lk];
#pragma unroll
        for (int ni = 0; ni < 4; ++ni)
            b[ni] = *(const f16x8*)&sB[cur][(wn + ni * 16 + lr) * 32 + lk];

#pragma unroll
        for (int mi = 0; mi < 4; ++mi)
#pragma unroll
            for (int ni = 0; ni < 4; ++ni)
                acc[mi][ni] = __builtin_amdgcn_mfma_f32_16x16x32_f16(
                    a[mi], b[ni], acc[mi][ni], 0, 0, 0);

        if (kt + 1 < NT) swrite(cur ^ 1);
    }

#pragma unroll
    for (int mi = 0; mi < 4; ++mi) {
#pragma unroll
        for (int ni = 0; ni < 4; ++ni) {
            const int row = m0 + wm + mi * 16 + (l >> 4) * 4;
            const int col = n0 + wn + ni * 16 + lr;
#pragma unroll
            for (int r2 = 0; r2 < 4; ++r2)
                C[(size_t)(row + r2) * NDIM + col] = acc[mi][ni][r2];
        }
    }
}

extern "C" void kernel_launch(void* const* d_in, const int* in_sizes, int n_in,
                              void* d_out, int out_size, void* d_ws, size_t ws_size,
                              hipStream_t stream) {
    const float* x     = (const float*)d_in[0];
    const float* scale = (const float*)d_in[1];
    const int*   qw    = (const int*)d_in[2];
    float*       out   = (float*)d_out;

    const size_t wtBytes = (size_t)NDIM * KDIM * 2;  // 32 MB
    const size_t xhBytes = (size_t)MDIM * KDIM * 2;  // 32 MB

    if (ws_size >= wtBytes + xhBytes) {
        unsigned short* wt = (unsigned short*)d_ws;
        unsigned short* xh = (unsigned short*)((char*)d_ws + wtBytes);
        convert_x<<<2048, 256, 0, stream>>>(x, xh, MDIM * KDIM / 8);
        dequant_transpose<<<dim3(KDIM / 64, NDIM / 64), 256, 0, stream>>>(qw, scale, wt);
        gemm_il<<<dim3(256), 512, 0, stream>>>(xh, wt, out);
    } else if (ws_size >= wtBytes) {
        unsigned short* wt = (unsigned short*)d_ws;
        dequant_transpose<<<dim3(KDIM / 64, NDIM / 64), 256, 0, stream>>>(qw, scale, wt);
        gemm_bt<<<dim3(NDIM / 128, MDIM / 128), 256, 0, stream>>>(x, wt, out);
    } else {
        zero_fill<<<(out_size + 255) / 256, 256, 0, stream>>>(out, out_size);
    }
}

// Round 8
// 153.036 us; speedup vs baseline: 1.0389x; 1.0248x over previous
//
#include <hip/hip_runtime.h>

// W4A16 GEMM, M=N=K=4096, GROUP=128, zp=8.
// Inputs (harness presents fp16 as f32): x f32[M,K], scale f32[32,N],
// q_weight int32[K,N] (0..15). Output f32[M,N].
//
// Fast path (ws >= 64MB):
//   P0 convert_x: x f32 -> Xh fp16 [M,K]
//   P1 dequant_transpose: q -> Wt fp16 [N,K]
//   P2 gemm_p4: 256x256 tile, BK=64, 8 waves, dbuf LDS, counted vmcnt(8),
//      read-side XOR swizzle (conflicts=0 verified r5), XCD swizzle.
//      NEW vs r7: read bursts PINNED with sched_barrier(0) so they issue
//      before the phase barrier (compiler was sinking them to just-in-time,
//      VGPR=100 proved it); quadrant order chosen to cap frag liveness.
// Fallback (ws >= 32MB): proven round-3 reg-staged 128x128 GEMM.

#define MDIM 4096
#define NDIM 4096
#define KDIM 4096

typedef __attribute__((ext_vector_type(8))) _Float16 f16x8;
typedef __attribute__((ext_vector_type(4))) float    f32x4;
typedef __attribute__((ext_vector_type(4))) int      i32x4;

__device__ __forceinline__ unsigned short f2h(float f) {
    union { _Float16 h; unsigned short u; } v;
    v.h = (_Float16)f;  // RNE
    return v.u;
}

// ---------------- diagnostic fallback ----------------
__global__ void zero_fill(float* __restrict__ out, int n) {
    int i = blockIdx.x * blockDim.x + threadIdx.x;
    if (i < n) out[i] = 0.f;
}

// ---------------- P0: x f32 -> fp16 ----------------
__global__ void convert_x(const float* __restrict__ x,
                          unsigned short* __restrict__ xh, int n8) {
    int i = blockIdx.x * blockDim.x + threadIdx.x;
    const int stride = gridDim.x * blockDim.x;
    for (; i < n8; i += stride) {
        const float4 a = ((const float4*)x)[(size_t)i * 2];
        const float4 b = ((const float4*)x)[(size_t)i * 2 + 1];
        f16x8 r;
        r[0] = (_Float16)a.x; r[1] = (_Float16)a.y;
        r[2] = (_Float16)a.z; r[3] = (_Float16)a.w;
        r[4] = (_Float16)b.x; r[5] = (_Float16)b.y;
        r[6] = (_Float16)b.z; r[7] = (_Float16)b.w;
        *(f16x8*)&xh[(size_t)i * 8] = r;
    }
}

// ---------------- P1: dequant + transpose ----------------
__global__ void dequant_transpose(const int* __restrict__ q,
                                  const float* __restrict__ scale,
                                  unsigned short* __restrict__ wt) {
    __shared__ unsigned short lds[64][65];
    const int t  = threadIdx.x;
    const int k0 = blockIdx.x * 64;
    const int n0 = blockIdx.y * 64;
    const int g  = k0 >> 7;

    const int r  = t >> 4;
    const int c4 = (t & 15) * 4;

    float4 s = *(const float4*)&scale[(size_t)g * NDIM + n0 + c4];

#pragma unroll
    for (int p = 0; p < 4; ++p) {
        const int kl = r + p * 16;
        int4 qv = *(const int4*)&q[(size_t)(k0 + kl) * NDIM + n0 + c4];
        lds[kl][c4 + 0] = f2h((float)(qv.x - 8) * s.x);
        lds[kl][c4 + 1] = f2h((float)(qv.y - 8) * s.y);
        lds[kl][c4 + 2] = f2h((float)(qv.z - 8) * s.z);
        lds[kl][c4 + 3] = f2h((float)(qv.w - 8) * s.w);
    }
    __syncthreads();

    const int kc = (t & 15) * 4;
#pragma unroll
    for (int p = 0; p < 4; ++p) {
        const int nl = (t >> 4) + p * 16;
        ushort4 o;
        o.x = lds[kc + 0][nl];
        o.y = lds[kc + 1][nl];
        o.z = lds[kc + 2][nl];
        o.w = lds[kc + 3][nl];
        *(ushort4*)&wt[(size_t)(n0 + nl) * KDIM + k0 + kc] = o;
    }
}

// ---------------- P2 fast: 256x256 8-wave 4-phase pinned GEMM ----------------
// Phases per K-tile (quadrants of wave's 128x64 output):
//   P0: read af[0-3](8) + bf[0-1](4) -> Q(mi0-3,ni0-1)
//   P1: read bf[2-3](4)              -> Q(mi0-3,ni2-3)   [af03 dies here]
//   P2: read af[4-7](8) + stageB     -> Q(mi4-7,ni2-3)
//   P3: stageA                       -> Q(mi4-7,ni0-1)
// Staging safety: all sB ds_reads (P0,P1) complete before P1-end barrier
// (consumed by Q(0,2) via compiler lgkm waits) -> stageB in P2 safe; all sA
// reads complete before P2-end barrier -> stageA in P3 safe. stage targets
// buf bsel (freed), awaited by vmcnt at tile kt+2.
__global__ __launch_bounds__(512, 2) void gemm_p4(const unsigned short* __restrict__ A,
                                                  const unsigned short* __restrict__ Bt,
                                                  float* __restrict__ C) {
    __shared__ unsigned short lds[65536];  // 128 KiB: 2 x (A 16384 + B 16384)

    const int t = threadIdx.x;
    const int w = t >> 6;   // wave 0..7
    const int l = t & 63;

    // XCD-aware bijective swizzle: 256 wgs, 8 XCDs -> 32 contiguous tiles/XCD
    const int orig = blockIdx.x;
    const int wg = (orig & 7) * 32 + (orig >> 3);
    const int bx = wg & 15;   // N tile
    const int by = wg >> 4;   // M tile
    const int m0 = by * 256;
    const int n0 = bx * 256;

    const int wr = w >> 2;    // 0..1 : wave row (128 rows)
    const int wc = w & 3;     // 0..3 : wave col (64 cols)

    // ---- staging geometry (per-lane swizzled source; LDS dest linear) ----
    const int lr8 = l >> 3;                  // row within 8-row group
    const int sc  = ((l & 7) ^ lr8) * 8;     // swizzled source col (halfs)
    const unsigned short* pa = A  + (size_t)(m0 + w * 8 + lr8) * KDIM + sc;
    const unsigned short* pb = Bt + (size_t)(n0 + w * 8 + lr8) * KDIM + sc;

    auto stageA = [&](int buf, int kt) {
        const int kof = kt * 64;
        unsigned short* base = &lds[buf * 32768];
#pragma unroll
        for (int i = 0; i < 4; ++i)
            __builtin_amdgcn_global_load_lds(
                (const __attribute__((address_space(1))) unsigned int*)(pa + (size_t)i * 64 * KDIM + kof),
                (__attribute__((address_space(3))) unsigned int*)(base + i * 4096 + w * 512), 16, 0, 0);
    };
    auto stageB = [&](int buf, int kt) {
        const int kof = kt * 64;
        unsigned short* base = &lds[buf * 32768 + 16384];
#pragma unroll
        for (int i = 0; i < 4; ++i)
            __builtin_amdgcn_global_load_lds(
                (const __attribute__((address_space(1))) unsigned int*)(pb + (size_t)i * 64 * KDIM + kof),
                (__attribute__((address_space(3))) unsigned int*)(base + i * 4096 + w * 512), 16, 0, 0);
    };

    // ---- fragment-read geometry ----
    const int lr = l & 15;    // frag row
    const int hi = l >> 4;    // 0..3 : k sub-chunk
    const int ca0 = ((hi + 0) ^ (l & 7)) * 8;  // phys chunk offset, k-step 0
    const int ca1 = ((hi + 4) ^ (l & 7)) * 8;  // phys chunk offset, k-step 1
    const int arow = wr * 128 + lr;
    const int brow = wc * 64 + lr;

    f32x4 acc[8][4];
#pragma unroll
    for (int mi = 0; mi < 8; ++mi)
#pragma unroll
        for (int ni = 0; ni < 4; ++ni)
            acc[mi][ni] = (f32x4){0.f, 0.f, 0.f, 0.f};

    f16x8 af[4][2], bf[4][2];  // af holds one 4-row half-tile at a time

#define READ_AF(MI0)                                                        \
    _Pragma("unroll")                                                       \
    for (int mi = 0; mi < 4; ++mi) {                                        \
        af[mi][0] = *(const f16x8*)&sA[(arow + (MI0 + mi) * 16) * 64 + ca0];\
        af[mi][1] = *(const f16x8*)&sA[(arow + (MI0 + mi) * 16) * 64 + ca1];\
    }
#define READ_BF(NI0)                                                        \
    _Pragma("unroll")                                                       \
    for (int ni = NI0; ni < NI0 + 2; ++ni) {                                \
        bf[ni][0] = *(const f16x8*)&sB[(brow + ni * 16) * 64 + ca0];        \
        bf[ni][1] = *(const f16x8*)&sB[(brow + ni * 16) * 64 + ca1];        \
    }
#define QUAD(MI0, NI0)                                                      \
    __builtin_amdgcn_s_setprio(1);                                          \
    _Pragma("unroll")                                                       \
    for (int kk = 0; kk < 2; ++kk)                                          \
        _Pragma("unroll")                                                   \
        for (int mi = 0; mi < 4; ++mi)                                      \
            _Pragma("unroll")                                               \
            for (int ni = NI0; ni < NI0 + 2; ++ni)                          \
                acc[MI0 + mi][ni] = __builtin_amdgcn_mfma_f32_16x16x32_f16( \
                    af[mi][kk], bf[ni][kk], acc[MI0 + mi][ni], 0, 0, 0);    \
    __builtin_amdgcn_s_setprio(0);

    stageA(0, 0); stageB(0, 0);
    stageA(1, 1); stageB(1, 1);

    const int NT = KDIM / 64;  // 64
    for (int kt = 0; kt < NT; ++kt) {
        if (kt == NT - 1)
            asm volatile("s_waitcnt vmcnt(0)" ::: "memory");
        else
            asm volatile("s_waitcnt vmcnt(8)" ::: "memory");  // tile kt landed
        __builtin_amdgcn_sched_barrier(0);
        __builtin_amdgcn_s_barrier();                          // buf block-wide ready

        const int bsel = kt & 1;
        const unsigned short* sA = &lds[bsel * 32768];
        const unsigned short* sB = &lds[bsel * 32768 + 16384];
        const bool pre = (kt + 2 < NT);

        // ---- P0: af[0-3] + bf[0-1] -> Q(0,0) ----
        READ_AF(0); READ_BF(0);
        __builtin_amdgcn_sched_barrier(0);   // pin the burst: issue before barrier
        __builtin_amdgcn_s_barrier();
        QUAD(0, 0);
        __builtin_amdgcn_s_barrier();

        // ---- P1: bf[2-3] -> Q(0,2) ----
        READ_BF(2);
        __builtin_amdgcn_sched_barrier(0);
        __builtin_amdgcn_s_barrier();
        QUAD(0, 2);
        __builtin_amdgcn_s_barrier();        // all sB reads of this tile done

        // ---- P2: af[4-7] + stageB(kt+2) -> Q(4,2) ----
        READ_AF(4);
        if (pre) stageB(bsel, kt + 2);
        __builtin_amdgcn_sched_barrier(0);
        __builtin_amdgcn_s_barrier();
        QUAD(4, 2);
        __builtin_amdgcn_s_barrier();        // all sA reads of this tile done

        // ---- P3: stageA(kt+2) -> Q(4,0) ----
        if (pre) stageA(bsel, kt + 2);
        __builtin_amdgcn_sched_barrier(0);
        QUAD(4, 0);
        // next-iteration top vmcnt+barrier closes this phase
    }

#undef READ_AF
#undef READ_BF
#undef QUAD

    // epilogue: D layout col = lane&15, row = (lane>>4)*4 + reg
#pragma unroll
    for (int mi = 0; mi < 8; ++mi) {
#pragma unroll
        for (int ni = 0; ni < 4; ++ni) {
            const int row = m0 + wr * 128 + mi * 16 + hi * 4;
            const int col = n0 + wc * 64 + ni * 16 + lr;
#pragma unroll
            for (int r2 = 0; r2 < 4; ++r2)
                C[(size_t)(row + r2) * NDIM + col] = acc[mi][ni][r2];
        }
    }
}

// ---------------- P2 fallback: round-3 reg-staged GEMM (proven) ----------------
__global__ __launch_bounds__(256) void gemm_bt(const float* __restrict__ A,
                                               const unsigned short* __restrict__ Bt,
                                               float* __restrict__ C) {
    __shared__ unsigned short sA[2][128 * 32];
    __shared__ unsigned short sB[2][128 * 32];

    const int t = threadIdx.x;
    const int l = t & 63;
    const int w = t >> 6;

    const int m0 = blockIdx.y * 128;
    const int n0 = blockIdx.x * 128;

    const float*          Arow = A  + (size_t)m0 * KDIM;
    const unsigned short* Brow = Bt + (size_t)n0 * KDIM;

    const int r0 = t >> 2;
    const int c0 = (t & 3) * 8;

    float4 fa[4];
    i32x4  pb0, pb1;
    auto gload = [&](int kt) {
        const size_t oa0 = (size_t)r0 * KDIM + (size_t)kt * 32 + c0;
        const size_t oa1 = (size_t)(r0 + 64) * KDIM + (size_t)kt * 32 + c0;
        fa[0] = *(const float4*)(Arow + oa0);
        fa[1] = *(const float4*)(Arow + oa0 + 4);
        fa[2] = *(const float4*)(Arow + oa1);
        fa[3] = *(const float4*)(Arow + oa1 + 4);
        pb0 = *(const i32x4*)(Brow + oa0);
        pb1 = *(const i32x4*)(Brow + oa1);
    };
    auto pack8 = [&](float4 a, float4 b) {
        f16x8 r;
        r[0] = (_Float16)a.x; r[1] = (_Float16)a.y;
        r[2] = (_Float16)a.z; r[3] = (_Float16)a.w;
        r[4] = (_Float16)b.x; r[5] = (_Float16)b.y;
        r[6] = (_Float16)b.z; r[7] = (_Float16)b.w;
        return r;
    };
    auto swrite = [&](int buf) {
        *(f16x8*)&sA[buf][r0 * 32 + c0]        = pack8(fa[0], fa[1]);
        *(f16x8*)&sA[buf][(r0 + 64) * 32 + c0] = pack8(fa[2], fa[3]);
        *(i32x4*)&sB[buf][r0 * 32 + c0]        = pb0;
        *(i32x4*)&sB[buf][(r0 + 64) * 32 + c0] = pb1;
    };

    f32x4 acc[4][4];
#pragma unroll
    for (int mi = 0; mi < 4; ++mi)
#pragma unroll
        for (int ni = 0; ni < 4; ++ni)
            acc[mi][ni] = (f32x4){0.f, 0.f, 0.f, 0.f};

    const int wm = (w >> 1) * 64;
    const int wn = (w & 1) * 64;
    const int lr = l & 15;
    const int lk = (l >> 4) * 8;

    gload(0);
    swrite(0);

    const int NT = KDIM / 32;
    for (int kt = 0; kt < NT; ++kt) {
        const int cur = kt & 1;
        __syncthreads();
        if (kt + 1 < NT) gload(kt + 1);

        f16x8 a[4], b[4];
#pragma unroll
        for (int mi = 0; mi < 4; ++mi)
            a[mi] = *(const f16x8*)&sA[cur][(wm + mi * 16 + lr) * 32 + lk];
#pragma unroll
        for (int ni = 0; ni < 4; ++ni)
            b[ni] = *(const f16x8*)&sB[cur][(wn + ni * 16 + lr) * 32 + lk];

#pragma unroll
        for (int mi = 0; mi < 4; ++mi)
#pragma unroll
            for (int ni = 0; ni < 4; ++ni)
                acc[mi][ni] = __builtin_amdgcn_mfma_f32_16x16x32_f16(
                    a[mi], b[ni], acc[mi][ni], 0, 0, 0);

        if (kt + 1 < NT) swrite(cur ^ 1);
    }

#pragma unroll
    for (int mi = 0; mi < 4; ++mi) {
#pragma unroll
        for (int ni = 0; ni < 4; ++ni) {
            const int row = m0 + wm + mi * 16 + (l >> 4) * 4;
            const int col = n0 + wn + ni * 16 + lr;
#pragma unroll
            for (int r2 = 0; r2 < 4; ++r2)
                C[(size_t)(row + r2) * NDIM + col] = acc[mi][ni][r2];
        }
    }
}

extern "C" void kernel_launch(void* const* d_in, const int* in_sizes, int n_in,
                              void* d_out, int out_size, void* d_ws, size_t ws_size,
                              hipStream_t stream) {
    const float* x     = (const float*)d_in[0];
    const float* scale = (const float*)d_in[1];
    const int*   qw    = (const int*)d_in[2];
    float*       out   = (float*)d_out;

    const size_t wtBytes = (size_t)NDIM * KDIM * 2;  // 32 MB
    const size_t xhBytes = (size_t)MDIM * KDIM * 2;  // 32 MB

    if (ws_size >= wtBytes + xhBytes) {
        unsigned short* wt = (unsigned short*)d_ws;
        unsigned short* xh = (unsigned short*)((char*)d_ws + wtBytes);
        convert_x<<<2048, 256, 0, stream>>>(x, xh, MDIM * KDIM / 8);
        dequant_transpose<<<dim3(KDIM / 64, NDIM / 64), 256, 0, stream>>>(qw, scale, wt);
        gemm_p4<<<dim3(256), 512, 0, stream>>>(xh, wt, out);
    } else if (ws_size >= wtBytes) {
        unsigned short* wt = (unsigned short*)d_ws;
        dequant_transpose<<<dim3(KDIM / 64, NDIM / 64), 256, 0, stream>>>(qw, scale, wt);
        gemm_bt<<<dim3(NDIM / 128, MDIM / 128), 256, 0, stream>>>(x, wt, out);
    } else {
        zero_fill<<<(out_size + 255) / 256, 256, 0, stream>>>(out, out_size);
    }
}